// Round 8
// baseline (179.202 us; speedup 1.0000x reference)
//
#include <hip/hip_runtime.h>
#include <hip/hip_bf16.h>
#include <hip/hip_fp16.h>
#include <math.h>

#define N_NODES 50000
#define DEG     32
#define NBF     16       // nodes/block (k_mm); 50000 = 3125*16
#define NBLK    3125
#define TSZ     (N_NODES * 32)   // f16 elems per tower slice
#define EPSV    1e-5f

typedef __attribute__((ext_vector_type(8))) short short8;   // 8 bf16 (4 VGPRs)
typedef __attribute__((ext_vector_type(4))) float f32x4;
typedef __attribute__((ext_vector_type(2))) _Float16 h16x2; // -> v_pk_*_f16
typedef __attribute__((ext_vector_type(4))) unsigned int uint4v;

__device__ __forceinline__ unsigned int bfpack(float a, float b) {
    return (unsigned int)__bfloat16_as_ushort(__float2bfloat16(a)) |
           ((unsigned int)__bfloat16_as_ushort(__float2bfloat16(b)) << 16);
}

// ---------- K1: weight prep (first 144 blocks) + pretrans MFMA -> PsT/PdT ----------
// Round-5 verified structure; ONLY change: stores go to TOWER-MAJOR layout
// [T][N][32] (same values, same 16B stores, different addresses).
__global__ __launch_bounds__(256) void k_proj(const float* __restrict__ h,
        const float* __restrict__ W_pre, const float* __restrict__ b_pre,
        const float* __restrict__ W_post, const float* __restrict__ W_mix,
        __hip_bfloat16* __restrict__ WeffT, __hip_bfloat16* __restrict__ WmixT,
        _Float16* __restrict__ PdT, _Float16* __restrict__ PsT, float sc, float isc) {
    int tid = threadIdx.x, w = tid >> 6, lane = tid & 63;
    int nb = blockIdx.x * 64;

    if (blockIdx.x < 144) {
        int i = blockIdx.x * 256 + tid;          // 36864 exact
        if (i < 20480) {
            int k = i % 160, to = i / 160, o = to & 31, t = to >> 5;
            const float* Wt = W_post + t * 416 * 32;
            float v;
            if (k < 32) v = Wt[k * 32 + o];
            else {
                int g = k - 32;   // [mean,mx,mn,std]; identity+amp+att folded (deg==32)
                v = Wt[(32 + g) * 32 + o] + sc * Wt[(160 + g) * 32 + o]
                  + isc * Wt[(288 + g) * 32 + o];
            }
            WeffT[i] = __float2bfloat16(v);
        } else {
            int j = i - 20480;
            int k = j & 127, o = j >> 7;
            WmixT[j] = __float2bfloat16(W_mix[k * 128 + o]);
        }
    }

    __shared__ __align__(16) __hip_bfloat16 sA[64][136];   // input tile (+8 pad)
    __shared__ __align__(16) _Float16 sP[2][64][136];      // output tiles Ps/Pd
    int colc = (tid & 31) * 4, rowb = tid >> 5;
#pragma unroll
    for (int i = 0; i < 8; ++i) {
        int row = i * 8 + rowb, n = nb + row;
        unsigned int lo = 0, hi = 0;
        if (n < N_NODES) {
            float4 f = *(const float4*)(h + n * 128 + colc);
            lo = bfpack(f.x, f.y); hi = bfpack(f.z, f.w);
        }
        *(uint2*)(&sA[row][colc]) = make_uint2(lo, hi);
    }
    __syncthreads();                                       // barrier 1
    int col = lane & 15, quad = lane >> 4, r0 = w * 16;
    short8 a[4];
#pragma unroll
    for (int t = 0; t < 4; ++t)
        a[t] = *(const short8*)(&sA[r0 + col][t * 32 + quad * 8]);

#pragma unroll
    for (int half = 0; half < 2; ++half) {       // 0: Ps, 1: Pd(+bias)
#pragma unroll
        for (int t = 0; t < 4; ++t) {
#pragma unroll
            for (int ct = 0; ct < 2; ++ct) {
                int o = ct * 16 + col;
                const float* wp = W_pre + t * 2048 + (half * 32 + quad * 8) * 32 + o;
                unsigned int bw0 = bfpack(wp[0],   wp[32]);
                unsigned int bw1 = bfpack(wp[64],  wp[96]);
                unsigned int bw2 = bfpack(wp[128], wp[160]);
                unsigned int bw3 = bfpack(wp[192], wp[224]);
                uint4v bwv = {bw0, bw1, bw2, bw3};
                short8 b = __builtin_bit_cast(short8, bwv);
                f32x4 acc = {0.f, 0.f, 0.f, 0.f};
                acc = __builtin_amdgcn_mfma_f32_16x16x32_bf16(a[t], b, acc, 0, 0, 0);
                float bp = half ? b_pre[t * 32 + o] : 0.f;
#pragma unroll
                for (int r = 0; r < 4; ++r)
                    sP[half][r0 + quad * 4 + r][t * 32 + o] =
                        __float2half(acc[r] + bp);
            }
        }
    }
    __syncthreads();                                       // barrier 2

    // tower-major coalesced stores: seg -> (tower = seg>>2, s4 = seg&3)
#pragma unroll
    for (int half = 0; half < 2; ++half) {
        _Float16* dst = half ? PdT : PsT;
#pragma unroll
        for (int rr = 0; rr < 4; ++rr) {
            int chunk = rr * 256 + tid;
            int row = chunk >> 4, seg = chunk & 15, n = nb + row;
            int t = seg >> 2, s4 = seg & 3;
            if (n < N_NODES)
                *(uint4v*)(dst + t * TSZ + n * 32 + s4 * 8) =
                    *(const uint4v*)(&sP[half][row][seg * 8]);
        }
    }
}

// ---------- K2: tower-phased gather -> per-(node,tower) stats -> zG ----------
// Grid: tower-major block order (blocks [t*3125, (t+1)*3125) handle tower t)
// so the active gather footprint per phase is one 3.2 MB tower slice
// (fits each XCD's 4 MB L2). Quarter-wave owns one (node,tower): 16 lanes
// x 2ch (h16x2). Neighbor order u=0..31 and per-pair op sequence identical
// to the verified round-0 kernel -> stats bitwise identical.
__global__ __launch_bounds__(256) void k_gather(const int* __restrict__ src,
        const _Float16* __restrict__ PsT, const _Float16* __restrict__ PdT,
        unsigned int* __restrict__ zG) {
    int tid = threadIdx.x, w = tid >> 6, lane = tid & 63;
    int bx = blockIdx.x;
    int t = bx / NBLK, nb = (bx - t * NBLK) * 16;
    int qw = lane >> 4, lq = lane & 15;
    int row = w * 4 + qw, n = nb + row;
    int cq2 = lq * 2;                       // channel pair within tower
    const _Float16* base = PsT + t * TSZ;

    int vsrc0 = src[n * DEG + lq];          // neighbors 0..15
    int vsrc1 = src[n * DEG + 16 + lq];     // neighbors 16..31
    unsigned int pdu = *(const unsigned int*)(PdT + t * TSZ + n * 32 + cq2);
    h16x2 pd = __builtin_bit_cast(h16x2, pdu);

    const h16x2 zeroh = {(_Float16)0.f, (_Float16)0.f};
    const h16x2 bigh  = {(_Float16)65504.f, (_Float16)65504.f};
    h16x2 sum = zeroh, sq = zeroh, mx = zeroh, mn = bigh;

#pragma unroll
    for (int j0 = 0; j0 < DEG; j0 += 16) {
        unsigned int pv[16];
#pragma unroll
        for (int u2 = 0; u2 < 16; ++u2) {
            int u = j0 + u2;
            int s = __shfl(u < 16 ? vsrc0 : vsrc1, (lane & 48) | (u & 15));
            pv[u2] = *(const unsigned int*)(base + s * 32 + cq2);
        }
#pragma unroll
        for (int u2 = 0; u2 < 16; ++u2) {
            h16x2 f = __builtin_bit_cast(h16x2, pv[u2]);
            h16x2 e = __builtin_elementwise_max(f + pd, zeroh);
            sum += e; sq = e * e + sq;
            mx = __builtin_elementwise_max(mx, e);
            mn = __builtin_elementwise_min(mn, e);
        }
    }
    float mean0 = (float)sum.x * (1.f / DEG), mean1 = (float)sum.y * (1.f / DEG);
    float sd0 = sqrtf(fmaxf((float)sq.x * (1.f / DEG) - mean0 * mean0, 0.f) + EPSV);
    float sd1 = sqrtf(fmaxf((float)sq.y * (1.f / DEG) - mean1 * mean1, 0.f) + EPSV);
    // zG: [n][t][stat(mean,mx,mn,sd)][16 uints]
    unsigned int* zr = zG + ((size_t)n * 4 + t) * 64;
    zr[lq]      = bfpack(mean0, mean1);
    zr[16 + lq] = bfpack((float)mx.x, (float)mx.y);
    zr[32 + lq] = bfpack((float)mn.x, (float)mn.y);
    zr[48 + lq] = bfpack(sd0, sd1);
}

// ---------- K3: build sZ from h + zG, then posttrans + mix (verbatim B/C) ----------
__global__ __launch_bounds__(256) void k_mm(const float* __restrict__ h,
        const unsigned int* __restrict__ zG, const __hip_bfloat16* __restrict__ WeffT,
        const __hip_bfloat16* __restrict__ WmixT, const float* __restrict__ b_post,
        const float* __restrict__ b_mix, float* __restrict__ out) {
    __shared__ __align__(16) __hip_bfloat16 sZ[NBF][648];
    __shared__ __align__(16) __hip_bfloat16 sHp[NBF][136];
    int tid = threadIdx.x, w = tid >> 6, lane = tid & 63;
    int nb = blockIdx.x * NBF;

    // ---- Phase A': fill sZ rows. r = tid>>4, j = tid&15 ----
    {
        int r = tid >> 4, j = tid & 15, n = nb + r;
        unsigned int* zrow = (unsigned int*)(&sZ[r][0]);   // 324 uints/row
        // h part: 8 channels per thread (same bfpack conversion as round-0)
        int t = j >> 2, o8 = (j & 3) * 8;                  // within-tower offset
        const float* hp = h + n * 128 + t * 32 + o8;
        float4 f0 = *(const float4*)(hp);
        float4 f1 = *(const float4*)(hp + 4);
        int ho = t * 80 + (o8 >> 1);
        zrow[ho + 0] = bfpack(f0.x, f0.y);  zrow[ho + 1] = bfpack(f0.z, f0.w);
        zrow[ho + 2] = bfpack(f1.x, f1.y);  zrow[ho + 3] = bfpack(f1.z, f1.w);
        // stats: 16 uints per thread, pure copy (already bf16-packed)
        const unsigned int* zg = zG + (size_t)n * 256;
#pragma unroll
        for (int k = 0; k < 16; ++k) {
            int tt = k >> 2, st = k & 3;
            zrow[tt * 80 + 16 + st * 16 + j] = zg[tt * 64 + st * 16 + j];
        }
    }
    __syncthreads();

    // ---- Phase B: posttrans MFMA; 8 col-tiles over 4 waves (2 each) ----
    int col = lane & 15, quad = lane >> 4;
#pragma unroll
    for (int i = 0; i < 2; ++i) {
        int ct = w * 2 + i, t = ct >> 1, nt = ct & 1;
        f32x4 acc = {0.f, 0.f, 0.f, 0.f};
        int oc = t * 32 + nt * 16 + col;
        const __hip_bfloat16* wrow = WeffT + oc * 160 + quad * 8;
#pragma unroll
        for (int ks = 0; ks < 5; ++ks) {
            short8 a = *(const short8*)(&sZ[col][t * 160 + ks * 32 + quad * 8]);
            short8 b = *(const short8*)(wrow + ks * 32);
            acc = __builtin_amdgcn_mfma_f32_16x16x32_bf16(a, b, acc, 0, 0, 0);
        }
        float bp = b_post[oc];
#pragma unroll
        for (int r = 0; r < 4; ++r)
            sHp[quad * 4 + r][oc] = __float2bfloat16(fmaxf(acc[r] + bp, 0.f));
    }
    __syncthreads();

    // ---- Phase C: mix MFMA + leaky ReLU + residual ----
#pragma unroll
    for (int i = 0; i < 2; ++i) {
        int nt = w * 2 + i;
        f32x4 acc = {0.f, 0.f, 0.f, 0.f};
        int oc = nt * 16 + col;
        const __hip_bfloat16* wrow = WmixT + oc * 128 + quad * 8;
#pragma unroll
        for (int ks = 0; ks < 4; ++ks) {
            short8 a = *(const short8*)(&sHp[col][ks * 32 + quad * 8]);
            short8 b = *(const short8*)(wrow + ks * 32);
            acc = __builtin_amdgcn_mfma_f32_16x16x32_bf16(a, b, acc, 0, 0, 0);
        }
        float bm = b_mix[oc];
#pragma unroll
        for (int r = 0; r < 4; ++r) {
            int n = nb + quad * 4 + r;
            float m = acc[r] + bm;
            m = m > 0.f ? m : 0.01f * m;
            out[n * 128 + oc] = h[n * 128 + oc] + m;
        }
    }
}

extern "C" void kernel_launch(void* const* d_in, const int* in_sizes, int n_in,
                              void* d_out, int out_size, void* d_ws, size_t ws_size,
                              hipStream_t stream) {
    const float* h      = (const float*)d_in[0];
    const int*   src    = (const int*)d_in[1];
    // d_in[2] = dst: structurally repeat(arange(N), DEG) -> unused
    const float* W_pre  = (const float*)d_in[3];
    const float* b_pre  = (const float*)d_in[4];
    const float* W_post = (const float*)d_in[5];
    const float* b_post = (const float*)d_in[6];
    const float* W_mix  = (const float*)d_in[7];
    const float* b_mix  = (const float*)d_in[8];
    float* out = (float*)d_out;

    char* ws = (char*)d_ws;
    __hip_bfloat16* WeffT = (__hip_bfloat16*)ws;                      // 40960 B
    __hip_bfloat16* WmixT = (__hip_bfloat16*)(ws + 40960);            // 32768 B
    _Float16*       PsT   = (_Float16*)(ws + 81920);                  // 12.8 MB
    _Float16*       PdT   = (_Float16*)(ws + 81920 + 12800000);       // 12.8 MB
    unsigned int*   zG    = (unsigned int*)(ws + 81920 + 25600000);   // 12.8 MB

    double scd = log(33.0) / log(5.0);    // deg==32 constant
    float sc = (float)scd, isc = (float)(1.0 / scd);

    hipLaunchKernelGGL(k_proj, dim3((N_NODES + 63) / 64), dim3(256), 0, stream,
                       h, W_pre, b_pre, W_post, W_mix, WeffT, WmixT, PdT, PsT, sc, isc);
    hipLaunchKernelGGL(k_gather, dim3(NBLK * 4), dim3(256), 0, stream,
                       src, PsT, PdT, zG);
    hipLaunchKernelGGL(k_mm, dim3(NBLK), dim3(256), 0, stream,
                       h, zG, WeffT, WmixT, b_post, b_mix, out);
}